// Round 2
// baseline (14779.147 us; speedup 1.0000x reference)
//
#include <hip/hip_runtime.h>
#include <math.h>

#define BB   2048
#define TT   100
#define DD   128
#define HH   256
#define NEGF -1.0e9f

__device__ __forceinline__ float sigmoidf_(float x){ return 1.0f/(1.0f+expf(-x)); }

__global__ __launch_bounds__(256) void k_zero_i32(int* __restrict__ p, int n){
  int i = blockIdx.x*256 + threadIdx.x;
  if(i < n) p[i] = 0;
}

// Fused gates GEMM + LSTM cell.
// gates[b,n] = sum_k X[b,k]*Wih[n,k] + sum_k H[b,k]*Whh[n,k]  (bias added in cell phase)
// Block: BM=128 rows x 16 j-columns (x 4 gate strips -> 64 logical cols). 256 threads, 8x4 micro.
__global__ __launch_bounds__(256) void k_gates_cell(
    const float* __restrict__ Xp, int ldx,          // may be null (x==0)
    const float* __restrict__ Hp,                   // may be null (h==0)
    const float* __restrict__ Wih, const float* __restrict__ Whh,
    const float* __restrict__ bih, const float* __restrict__ bhh,
    const float* __restrict__ Cp,                   // may be null (c==0)
    float* __restrict__ Hout, float* __restrict__ Cout,
    float* __restrict__ Hcopy, int hstride)         // optional extra h sink (enc states)
{
  __shared__ alignas(16) float smem[8704];          // Xs[32][132] + Ws[32][68]; reused as gsm[128][68]
  float* Xs = smem;
  float* Ws = smem + 4224;
  const int tid = threadIdx.x;
  const int tx = tid & 15, ty = tid >> 4;
  const int j0 = blockIdx.x * 16;
  const int m0 = blockIdx.y * 128;

  float acc[8][4];
  #pragma unroll
  for(int i=0;i<8;i++)
    #pragma unroll
    for(int j=0;j<4;j++) acc[i][j] = 0.f;

  for(int phase=0; phase<2; phase++){
    const float* Am; int lda; const float* Wm; int ldw; int nt;
    if(phase==0){ if(!Xp) continue; Am=Xp; lda=ldx; Wm=Wih; ldw=DD; nt=4; }
    else        { if(!Hp) continue; Am=Hp; lda=HH;  Wm=Whh; ldw=HH; nt=8; }
    for(int kt=0; kt<nt; kt++){
      const int k0 = kt*32;
      #pragma unroll
      for(int it=0; it<4; it++){                    // X tile: 128 rows x 32 k, transposed store
        int q = it*256 + tid; int m = q>>3; int kq = (q&7)<<2;
        const float4 v = *(const float4*)(Am + (size_t)(m0+m)*lda + k0 + kq);
        Xs[(kq+0)*132+m]=v.x; Xs[(kq+1)*132+m]=v.y; Xs[(kq+2)*132+m]=v.z; Xs[(kq+3)*132+m]=v.w;
      }
      #pragma unroll
      for(int it=0; it<2; it++){                    // W tile: 64 logical cols x 32 k
        int q = it*256 + tid; int c = q>>3; int kq = (q&7)<<2;
        int n = (c>>4)*HH + j0 + (c&15);            // strip*H + j0 + jj
        const float4 v = *(const float4*)(Wm + (size_t)n*ldw + k0 + kq);
        Ws[(kq+0)*68+c]=v.x; Ws[(kq+1)*68+c]=v.y; Ws[(kq+2)*68+c]=v.z; Ws[(kq+3)*68+c]=v.w;
      }
      __syncthreads();
      #pragma unroll
      for(int kk=0; kk<32; kk++){
        const float4 a0 = *(const float4*)&Xs[kk*132 + ty*8];
        const float4 a1 = *(const float4*)&Xs[kk*132 + ty*8 + 4];
        const float4 bv = *(const float4*)&Ws[kk*68 + tx*4];
        const float a[8] = {a0.x,a0.y,a0.z,a0.w,a1.x,a1.y,a1.z,a1.w};
        const float b[4] = {bv.x,bv.y,bv.z,bv.w};
        #pragma unroll
        for(int i=0;i<8;i++)
          #pragma unroll
          for(int j=0;j<4;j++)
            acc[i][j] = fmaf(a[i], b[j], acc[i][j]);
      }
      __syncthreads();
    }
  }

  // stash raw gates to LDS, remap threads for the cell
  float* gsm = smem;                                // [128][68]
  #pragma unroll
  for(int i=0;i<8;i++){
    *(float4*)&gsm[(ty*8+i)*68 + tx*4] = make_float4(acc[i][0],acc[i][1],acc[i][2],acc[i][3]);
  }
  __syncthreads();

  {
    const int m   = tid >> 1;
    const int jj0 = (tid & 1) * 8;
    const int b   = m0 + m;
    #pragma unroll
    for(int i=0;i<8;i++){
      const int jj  = jj0 + i;
      const int col = j0 + jj;
      const float iv = gsm[m*68 +      jj] + bih[       col] + bhh[       col];
      const float fv = gsm[m*68 + 16 + jj] + bih[  HH + col] + bhh[  HH + col];
      const float gv = gsm[m*68 + 32 + jj] + bih[2*HH + col] + bhh[2*HH + col];
      const float ov = gsm[m*68 + 48 + jj] + bih[3*HH + col] + bhh[3*HH + col];
      const size_t idx = (size_t)b*HH + col;
      const float cp = Cp ? Cp[idx] : 0.f;
      const float cn = sigmoidf_(fv)*cp + sigmoidf_(iv)*tanhf(gv);
      const float hn = sigmoidf_(ov)*tanhf(cn);
      Cout[idx] = cn;
      Hout[idx] = hn;
      if(Hcopy) Hcopy[(size_t)b*hstride + col] = hn;
    }
  }
}

// Generic NT GEMM: C[m,n] = sum_k A[m,k]*Bm[n,k].  64x64 tile, 4x4 micro.
__global__ __launch_bounds__(256) void k_gemm_nt(
    const float* __restrict__ A, int lda,
    const float* __restrict__ Bm, int ldb,
    float* __restrict__ C, int ldc, int K)
{
  __shared__ alignas(16) float Xs[32*68];
  __shared__ alignas(16) float Ws[32*68];
  const int tid = threadIdx.x;
  const int tx = tid & 15, ty = tid >> 4;
  const int n0 = blockIdx.x*64, m0 = blockIdx.y*64;
  float acc[4][4];
  #pragma unroll
  for(int i=0;i<4;i++)
    #pragma unroll
    for(int j=0;j<4;j++) acc[i][j]=0.f;

  for(int k0=0; k0<K; k0+=32){
    #pragma unroll
    for(int it=0; it<2; it++){
      int q = it*256 + tid; int m = q>>3; int kq = (q&7)<<2;
      float4 v = *(const float4*)(A + (size_t)(m0+m)*lda + k0 + kq);
      Xs[(kq+0)*68+m]=v.x; Xs[(kq+1)*68+m]=v.y; Xs[(kq+2)*68+m]=v.z; Xs[(kq+3)*68+m]=v.w;
      v = *(const float4*)(Bm + (size_t)(n0+m)*ldb + k0 + kq);
      Ws[(kq+0)*68+m]=v.x; Ws[(kq+1)*68+m]=v.y; Ws[(kq+2)*68+m]=v.z; Ws[(kq+3)*68+m]=v.w;
    }
    __syncthreads();
    #pragma unroll
    for(int kk=0; kk<32; kk++){
      const float4 av = *(const float4*)&Xs[kk*68 + ty*4];
      const float4 bv = *(const float4*)&Ws[kk*68 + tx*4];
      const float a[4] = {av.x,av.y,av.z,av.w};
      const float b[4] = {bv.x,bv.y,bv.z,bv.w};
      #pragma unroll
      for(int i=0;i<4;i++)
        #pragma unroll
        for(int j=0;j<4;j++)
          acc[i][j] = fmaf(a[i], b[j], acc[i][j]);
    }
    __syncthreads();
  }
  #pragma unroll
  for(int i=0;i<4;i++){
    *(float4*)&C[(size_t)(m0+ty*4+i)*ldc + n0 + tx*4] =
        make_float4(acc[i][0],acc[i][1],acc[i][2],acc[i][3]);
  }
}

// In-place row transform: blend1_row <- blend1_row @ W1^T.  Block owns 32 full rows.
__global__ __launch_bounds__(256) void k_blend1(float* __restrict__ blend1,
                                                const float* __restrict__ W1)
{
  __shared__ alignas(16) float Af[32*260];          // rows x K, padded
  __shared__ alignas(16) float Ws[32*68];
  const int tid = threadIdx.x;
  const int tx = tid & 15, ty = tid >> 4;
  const size_t r0 = (size_t)blockIdx.x * 32;

  #pragma unroll
  for(int it=0; it<8; it++){
    int q = it*256 + tid; int m = q>>6; int kq = (q&63)<<2;
    *(float4*)&Af[m*260 + kq] = *(const float4*)(blend1 + (r0+m)*256 + kq);
  }
  __syncthreads();

  for(int nc=0; nc<4; nc++){
    const int n0 = nc*64;
    float acc[2][4];
    #pragma unroll
    for(int i=0;i<2;i++)
      #pragma unroll
      for(int j=0;j<4;j++) acc[i][j]=0.f;
    for(int kt=0; kt<8; kt++){
      const int k0 = kt*32;
      __syncthreads();
      #pragma unroll
      for(int it=0; it<2; it++){
        int q = it*256 + tid; int c = q>>3; int kq = (q&7)<<2;
        const float4 v = *(const float4*)(W1 + (size_t)(n0+c)*256 + k0 + kq);
        Ws[(kq+0)*68+c]=v.x; Ws[(kq+1)*68+c]=v.y; Ws[(kq+2)*68+c]=v.z; Ws[(kq+3)*68+c]=v.w;
      }
      __syncthreads();
      #pragma unroll
      for(int kk=0; kk<32; kk++){
        const float4 bv = *(const float4*)&Ws[kk*68 + tx*4];
        const float a0 = Af[(ty*2+0)*260 + k0 + kk];
        const float a1 = Af[(ty*2+1)*260 + k0 + kk];
        acc[0][0]=fmaf(a0,bv.x,acc[0][0]); acc[0][1]=fmaf(a0,bv.y,acc[0][1]);
        acc[0][2]=fmaf(a0,bv.z,acc[0][2]); acc[0][3]=fmaf(a0,bv.w,acc[0][3]);
        acc[1][0]=fmaf(a1,bv.x,acc[1][0]); acc[1][1]=fmaf(a1,bv.y,acc[1][1]);
        acc[1][2]=fmaf(a1,bv.z,acc[1][2]); acc[1][3]=fmaf(a1,bv.w,acc[1][3]);
      }
    }
    #pragma unroll
    for(int i=0;i<2;i++){
      *(float4*)&blend1[(r0 + ty*2 + i)*256 + n0 + tx*4] =
          make_float4(acc[i][0],acc[i][1],acc[i][2],acc[i][3]);
    }
  }
}

// Pointer scores + argmax + softmax + gather.  One block per batch row.
__global__ __launch_bounds__(256) void k_scores(
    const float* __restrict__ blend1,   // [B,T,256]
    const float* __restrict__ blend2,   // [B,256]
    const float* __restrict__ vt,       // [256]
    const float* __restrict__ targets,  // [B,T,128]
    int*  __restrict__ selected,        // [B,T]
    float* __restrict__ dec_in,         // [B,128]
    float* __restrict__ out,            // [B,T,T]
    int s)
{
  __shared__ float vt_s[256], b2_s[256], sc[128];
  __shared__ float M_s, S_s;
  __shared__ int sel_s;
  const int b = blockIdx.x;
  const int tid = threadIdx.x;
  const int lane = tid & 63;
  const int wave = tid >> 6;

  vt_s[tid] = vt[tid];
  b2_s[tid] = blend2[(size_t)b*256 + tid];
  __syncthreads();

  // scores: wave w handles t = w, w+4, ...
  for(int it=0; it<25; it++){
    const int t = wave + it*4;
    const float* row = blend1 + ((size_t)b*TT + t)*256;
    float p = 0.f;
    #pragma unroll
    for(int r=0; r<4; r++){
      const int k = lane + r*64;
      p = fmaf(tanhf(row[k] + b2_s[k]), vt_s[k], p);
    }
    #pragma unroll
    for(int off=32; off>=1; off>>=1) p += __shfl_xor(p, off, 64);
    if(lane == 0) sc[t] = p;
  }
  __syncthreads();

  if(wave == 0){
    // mask, argmax (first-index tie-break), softmax denom -- over T=100
    float m1 = selected[(size_t)b*TT + lane] ? NEGF : sc[lane];
    sc[lane] = m1;
    float bestv = m1; int besti = lane;
    float m2 = 0.f;
    const int t2 = lane + 64;
    if(t2 < TT){
      m2 = selected[(size_t)b*TT + t2] ? NEGF : sc[t2];
      sc[t2] = m2;
      if(m2 > bestv){ bestv = m2; besti = t2; }
    }
    #pragma unroll
    for(int off=32; off>=1; off>>=1){
      const float ov = __shfl_xor(bestv, off, 64);
      const int   oi = __shfl_xor(besti, off, 64);
      if(ov > bestv || (ov == bestv && oi < besti)){ bestv = ov; besti = oi; }
    }
    float e = expf(m1 - bestv);
    if(t2 < TT) e += expf(m2 - bestv);
    #pragma unroll
    for(int off=32; off>=1; off>>=1) e += __shfl_xor(e, off, 64);
    if(lane == 0){
      M_s = bestv; S_s = e; sel_s = besti;
      selected[(size_t)b*TT + besti] = 1;   // for NEXT step; probs use pre-update mask
    }
  }
  __syncthreads();

  const int sel = sel_s;
  if(tid < TT){
    float p = expf(sc[tid] - M_s) / S_s;
    out[(size_t)b*TT*TT + (size_t)s*TT + tid] = fmaxf(p, 1e-9f);
  }
  if(tid < DD){
    dec_in[(size_t)b*DD + tid] = targets[((size_t)b*TT + sel)*DD + tid];
  }
}

extern "C" void kernel_launch(void* const* d_in, const int* in_sizes, int n_in,
                              void* d_out, int out_size, void* d_ws, size_t ws_size,
                              hipStream_t stream)
{
  (void)in_sizes; (void)n_in; (void)out_size; (void)ws_size;
  const float* targets  = (const float*)d_in[0];
  const float* h0       = (const float*)d_in[1];
  const float* c0       = (const float*)d_in[2];
  const float* enc_w_ih = (const float*)d_in[3];
  const float* enc_w_hh = (const float*)d_in[4];
  const float* enc_b_ih = (const float*)d_in[5];
  const float* enc_b_hh = (const float*)d_in[6];
  const float* dec_w_ih = (const float*)d_in[7];
  const float* dec_w_hh = (const float*)d_in[8];
  const float* dec_b_ih = (const float*)d_in[9];
  const float* dec_b_hh = (const float*)d_in[10];
  const float* W1       = (const float*)d_in[11];
  const float* W2       = (const float*)d_in[12];
  const float* vt       = (const float*)d_in[13];
  float* out = (float*)d_out;

  // workspace carve-up (~222 MB)
  float* ws      = (float*)d_ws;
  float* blend1  = ws;                               // B*T*256
  float* hA      = blend1 + (size_t)BB*TT*256;       // B*256 each
  float* hB      = hA + (size_t)BB*HH;
  float* cA      = hB + (size_t)BB*HH;
  float* cB      = cA + (size_t)BB*HH;
  float* blend2  = cB + (size_t)BB*HH;               // B*256
  float* dec_in  = blend2 + (size_t)BB*HH;           // B*128
  int*   selected= (int*)(dec_in + (size_t)BB*DD);   // B*T ints

  k_zero_i32<<<(BB*TT + 255)/256, 256, 0, stream>>>(selected, BB*TT);

  // ---- encoder: h written both to h-buffer and into blend1 slot (pre-W1) ----
  // parity: step t WRITES (t even -> hA, t odd -> hB); step t READS what t-1 wrote.
  for(int t=0; t<TT; t++){
    const float* Hp = (t==0) ? nullptr : ((t&1) ? hA : hB);
    const float* Cp = (t==0) ? nullptr : ((t&1) ? cA : cB);
    float* Ho = (t&1) ? hB : hA;
    float* Co = (t&1) ? cB : cA;
    k_gates_cell<<<dim3(16,16), 256, 0, stream>>>(
        targets + (size_t)t*DD, TT*DD,
        Hp, enc_w_ih, enc_w_hh, enc_b_ih, enc_b_hh, Cp,
        Ho, Co, blend1 + (size_t)t*256, TT*256);
  }

  // ---- blend1 = enc_states @ W1^T, in place ----
  k_blend1<<<BB*TT/32, 256, 0, stream>>>(blend1, W1);

  // ---- decoder ----
  for(int s=0; s<TT; s++){
    const float* Hp = (s==0) ? h0 : ((s&1) ? hA : hB);
    const float* Cp = (s==0) ? c0 : ((s&1) ? cA : cB);
    float* Ho = (s&1) ? hB : hA;
    float* Co = (s&1) ? cB : cA;
    const float* Xp = (s==0) ? nullptr : dec_in;   // first input is zeros
    k_gates_cell<<<dim3(16,16), 256, 0, stream>>>(
        Xp, DD, Hp, dec_w_ih, dec_w_hh, dec_b_ih, dec_b_hh, Cp,
        Ho, Co, nullptr, 0);
    k_gemm_nt<<<dim3(4,32), 256, 0, stream>>>(Ho, HH, W2, HH, blend2, HH, HH);
    k_scores<<<BB, 256, 0, stream>>>(blend1, blend2, vt, targets, selected,
                                     dec_in, out, s);
  }
}

// Round 3
// 14277.126 us; speedup vs baseline: 1.0352x; 1.0352x over previous
//
#include <hip/hip_runtime.h>
#include <math.h>

#define BB   2048
#define TT   100
#define DD   128
#define HH   256
#define NEGF -1.0e9f

__device__ __forceinline__ float sigmoidf_(float x){ return 1.0f/(1.0f+expf(-x)); }

// fast tanh: HW exp + HW rcp. |rel err| ~1e-7, clamped so e never overflows.
__device__ __forceinline__ float tanh_fast(float x){
  x = fminf(15.f, fmaxf(-15.f, x));
  const float e = __expf(x + x);
  return (e - 1.f) * __builtin_amdgcn_rcpf(e + 1.f);
}

__global__ __launch_bounds__(256) void k_zero_i32(int* __restrict__ p, int n){
  int i = blockIdx.x*256 + threadIdx.x;
  if(i < n) p[i] = 0;
}

// Fused gates GEMM + LSTM cell, v2.
// 128 threads, BM=64 rows x 16 j-cols (x4 gate strips interleaved: c = jj*4+strip).
// grid (16, 32) = 512 blocks -> 4 blocks/CU, 8 waves/CU.
// Thread (tx,ty): rows ty*8..+7, col jj=tx, all 4 gates in registers -> cell w/o LDS.
__global__ __launch_bounds__(128) void k_gates_cell(
    const float* __restrict__ Xp, int ldx,          // may be null (x==0)
    const float* __restrict__ Hp,                   // may be null (h==0)
    const float* __restrict__ Wih, const float* __restrict__ Whh,
    const float* __restrict__ bih, const float* __restrict__ bhh,
    const float* __restrict__ Cp,                   // may be null (c==0)
    float* __restrict__ Hout, float* __restrict__ Cout,
    float* __restrict__ Hcopy, int hstride)         // optional extra h sink
{
  __shared__ alignas(16) float Xs[32*68];           // [kk][m], m<64, pad 68
  __shared__ alignas(16) float Ws[32*68];           // [kk][c], c=jj*4+strip
  const int tid = threadIdx.x;
  const int tx = tid & 15;                          // jj
  const int ty = tid >> 4;                          // 0..7
  const int j0 = blockIdx.x * 16;
  const int m0 = blockIdx.y * 64;

  float acc[8][4];                                  // [row][gate strip]
  #pragma unroll
  for(int i=0;i<8;i++)
    #pragma unroll
    for(int s=0;s<4;s++) acc[i][s] = 0.f;

  for(int phase=0; phase<2; phase++){
    const float* Am; int lda; const float* Wm; int ldw; int nt;
    if(phase==0){ if(!Xp) continue; Am=Xp; lda=ldx; Wm=Wih; ldw=DD; nt=4; }
    else        { if(!Hp) continue; Am=Hp; lda=HH;  Wm=Whh; ldw=HH; nt=8; }
    for(int kt=0; kt<nt; kt++){
      const int k0 = kt*32;
      #pragma unroll
      for(int it=0; it<4; it++){                    // A tile: 64 rows x 32 k, transposed
        int q = it*128 + tid; int m = q>>3; int kq = (q&7)<<2;
        const float4 v = *(const float4*)(Am + (size_t)(m0+m)*lda + k0 + kq);
        Xs[(kq+0)*68+m]=v.x; Xs[(kq+1)*68+m]=v.y; Xs[(kq+2)*68+m]=v.z; Xs[(kq+3)*68+m]=v.w;
      }
      #pragma unroll
      for(int it=0; it<4; it++){                    // W tile: 64 cols (strip-interleaved)
        int q = it*128 + tid; int c = q>>3; int kq = (q&7)<<2;
        int n = (c&3)*HH + j0 + (c>>2);             // strip*H + j0 + jj
        const float4 v = *(const float4*)(Wm + (size_t)n*ldw + k0 + kq);
        Ws[(kq+0)*68+c]=v.x; Ws[(kq+1)*68+c]=v.y; Ws[(kq+2)*68+c]=v.z; Ws[(kq+3)*68+c]=v.w;
      }
      __syncthreads();
      #pragma unroll
      for(int kk=0; kk<32; kk++){
        const float4 a0 = *(const float4*)&Xs[kk*68 + ty*8];
        const float4 a1 = *(const float4*)&Xs[kk*68 + ty*8 + 4];
        const float4 bv = *(const float4*)&Ws[kk*68 + tx*4];
        const float a[8] = {a0.x,a0.y,a0.z,a0.w,a1.x,a1.y,a1.z,a1.w};
        const float g[4] = {bv.x,bv.y,bv.z,bv.w};
        #pragma unroll
        for(int i=0;i<8;i++)
          #pragma unroll
          for(int s=0;s<4;s++)
            acc[i][s] = fmaf(a[i], g[s], acc[i][s]);
      }
      __syncthreads();
    }
  }

  // cell epilogue, fully in registers
  const int col = j0 + tx;
  const float bi0 = bih[       col] + bhh[       col];
  const float bf0 = bih[  HH + col] + bhh[  HH + col];
  const float bg0 = bih[2*HH + col] + bhh[2*HH + col];
  const float bo0 = bih[3*HH + col] + bhh[3*HH + col];
  #pragma unroll
  for(int i=0;i<8;i++){
    const int b = m0 + ty*8 + i;
    const size_t idx = (size_t)b*HH + col;
    const float iv = acc[i][0] + bi0;
    const float fv = acc[i][1] + bf0;
    const float gv = acc[i][2] + bg0;
    const float ov = acc[i][3] + bo0;
    const float cp = Cp ? Cp[idx] : 0.f;
    const float cn = sigmoidf_(fv)*cp + sigmoidf_(iv)*tanhf(gv);
    const float hn = sigmoidf_(ov)*tanhf(cn);
    Cout[idx] = cn;
    Hout[idx] = hn;
    if(Hcopy) Hcopy[(size_t)b*hstride + col] = hn;
  }
}

// Generic NT GEMM: C[m,n] = sum_k A[m,k]*Bm[n,k].  64x64 tile, 4x4 micro.
__global__ __launch_bounds__(256) void k_gemm_nt(
    const float* __restrict__ A, int lda,
    const float* __restrict__ Bm, int ldb,
    float* __restrict__ C, int ldc, int K)
{
  __shared__ alignas(16) float Xs[32*68];
  __shared__ alignas(16) float Ws[32*68];
  const int tid = threadIdx.x;
  const int tx = tid & 15, ty = tid >> 4;
  const int n0 = blockIdx.x*64, m0 = blockIdx.y*64;
  float acc[4][4];
  #pragma unroll
  for(int i=0;i<4;i++)
    #pragma unroll
    for(int j=0;j<4;j++) acc[i][j]=0.f;

  for(int k0=0; k0<K; k0+=32){
    #pragma unroll
    for(int it=0; it<2; it++){
      int q = it*256 + tid; int m = q>>3; int kq = (q&7)<<2;
      float4 v = *(const float4*)(A + (size_t)(m0+m)*lda + k0 + kq);
      Xs[(kq+0)*68+m]=v.x; Xs[(kq+1)*68+m]=v.y; Xs[(kq+2)*68+m]=v.z; Xs[(kq+3)*68+m]=v.w;
      v = *(const float4*)(Bm + (size_t)(n0+m)*ldb + k0 + kq);
      Ws[(kq+0)*68+m]=v.x; Ws[(kq+1)*68+m]=v.y; Ws[(kq+2)*68+m]=v.z; Ws[(kq+3)*68+m]=v.w;
    }
    __syncthreads();
    #pragma unroll
    for(int kk=0; kk<32; kk++){
      const float4 av = *(const float4*)&Xs[kk*68 + ty*4];
      const float4 bv = *(const float4*)&Ws[kk*68 + tx*4];
      const float a[4] = {av.x,av.y,av.z,av.w};
      const float b[4] = {bv.x,bv.y,bv.z,bv.w};
      #pragma unroll
      for(int i=0;i<4;i++)
        #pragma unroll
        for(int j=0;j<4;j++)
          acc[i][j] = fmaf(a[i], b[j], acc[i][j]);
    }
    __syncthreads();
  }
  #pragma unroll
  for(int i=0;i<4;i++){
    *(float4*)&C[(size_t)(m0+ty*4+i)*ldc + n0 + tx*4] =
        make_float4(acc[i][0],acc[i][1],acc[i][2],acc[i][3]);
  }
}

// In-place row transform: blend1_row <- blend1_row @ W1^T.  Block owns 32 full rows.
__global__ __launch_bounds__(256) void k_blend1(float* __restrict__ blend1,
                                                const float* __restrict__ W1)
{
  __shared__ alignas(16) float Af[32*260];
  __shared__ alignas(16) float Ws[32*68];
  const int tid = threadIdx.x;
  const int tx = tid & 15, ty = tid >> 4;
  const size_t r0 = (size_t)blockIdx.x * 32;

  #pragma unroll
  for(int it=0; it<8; it++){
    int q = it*256 + tid; int m = q>>6; int kq = (q&63)<<2;
    *(float4*)&Af[m*260 + kq] = *(const float4*)(blend1 + (r0+m)*256 + kq);
  }
  __syncthreads();

  for(int nc=0; nc<4; nc++){
    const int n0 = nc*64;
    float acc[2][4];
    #pragma unroll
    for(int i=0;i<2;i++)
      #pragma unroll
      for(int j=0;j<4;j++) acc[i][j]=0.f;
    for(int kt=0; kt<8; kt++){
      const int k0 = kt*32;
      __syncthreads();
      #pragma unroll
      for(int it=0; it<2; it++){
        int q = it*256 + tid; int c = q>>3; int kq = (q&7)<<2;
        const float4 v = *(const float4*)(W1 + (size_t)(n0+c)*256 + k0 + kq);
        Ws[(kq+0)*68+c]=v.x; Ws[(kq+1)*68+c]=v.y; Ws[(kq+2)*68+c]=v.z; Ws[(kq+3)*68+c]=v.w;
      }
      __syncthreads();
      #pragma unroll
      for(int kk=0; kk<32; kk++){
        const float4 bv = *(const float4*)&Ws[kk*68 + tx*4];
        const float a0 = Af[(ty*2+0)*260 + k0 + kk];
        const float a1 = Af[(ty*2+1)*260 + k0 + kk];
        acc[0][0]=fmaf(a0,bv.x,acc[0][0]); acc[0][1]=fmaf(a0,bv.y,acc[0][1]);
        acc[0][2]=fmaf(a0,bv.z,acc[0][2]); acc[0][3]=fmaf(a0,bv.w,acc[0][3]);
        acc[1][0]=fmaf(a1,bv.x,acc[1][0]); acc[1][1]=fmaf(a1,bv.y,acc[1][1]);
        acc[1][2]=fmaf(a1,bv.z,acc[1][2]); acc[1][3]=fmaf(a1,bv.w,acc[1][3]);
      }
    }
    #pragma unroll
    for(int i=0;i<2;i++){
      *(float4*)&blend1[(r0 + ty*2 + i)*256 + n0 + tx*4] =
          make_float4(acc[i][0],acc[i][1],acc[i][2],acc[i][3]);
    }
  }
}

// Pointer scores + argmax + softmax + gather.  One block per batch row.
__global__ __launch_bounds__(256) void k_scores(
    const float* __restrict__ blend1,   // [B,T,256]
    const float* __restrict__ blend2,   // [B,256]
    const float* __restrict__ vt,       // [256]
    const float* __restrict__ targets,  // [B,T,128]
    int*  __restrict__ selected,        // [B,T]
    float* __restrict__ dec_in,         // [B,128]
    float* __restrict__ out,            // [B,T,T]
    int s)
{
  __shared__ float vt_s[256], b2_s[256], sc[128];
  __shared__ float M_s, S_s;
  __shared__ int sel_s;
  const int b = blockIdx.x;
  const int tid = threadIdx.x;
  const int lane = tid & 63;
  const int wave = tid >> 6;

  vt_s[tid] = vt[tid];
  b2_s[tid] = blend2[(size_t)b*256 + tid];
  __syncthreads();

  const float4 bb = *(const float4*)&b2_s[lane*4];
  const float4 vv = *(const float4*)&vt_s[lane*4];

  // scores: wave w handles t = w, w+4, ...  one float4 per lane covers the row
  for(int it=0; it<25; it++){
    const int t = wave + it*4;
    const float4 x = *(const float4*)(blend1 + ((size_t)b*TT + t)*256 + lane*4);
    float p;
    p = tanh_fast(x.x + bb.x) * vv.x;
    p = fmaf(tanh_fast(x.y + bb.y), vv.y, p);
    p = fmaf(tanh_fast(x.z + bb.z), vv.z, p);
    p = fmaf(tanh_fast(x.w + bb.w), vv.w, p);
    #pragma unroll
    for(int off=32; off>=1; off>>=1) p += __shfl_xor(p, off, 64);
    if(lane == 0) sc[t] = p;
  }
  __syncthreads();

  if(wave == 0){
    // mask, argmax (first-index tie-break), softmax denom -- over T=100
    float m1 = selected[(size_t)b*TT + lane] ? NEGF : sc[lane];
    sc[lane] = m1;
    float bestv = m1; int besti = lane;
    float m2 = 0.f;
    const int t2 = lane + 64;
    if(t2 < TT){
      m2 = selected[(size_t)b*TT + t2] ? NEGF : sc[t2];
      sc[t2] = m2;
      if(m2 > bestv){ bestv = m2; besti = t2; }
    }
    #pragma unroll
    for(int off=32; off>=1; off>>=1){
      const float ov = __shfl_xor(bestv, off, 64);
      const int   oi = __shfl_xor(besti, off, 64);
      if(ov > bestv || (ov == bestv && oi < besti)){ bestv = ov; besti = oi; }
    }
    float e = __expf(m1 - bestv);
    if(t2 < TT) e += __expf(m2 - bestv);
    #pragma unroll
    for(int off=32; off>=1; off>>=1) e += __shfl_xor(e, off, 64);
    if(lane == 0){
      M_s = bestv; S_s = e; sel_s = besti;
      selected[(size_t)b*TT + besti] = 1;   // for NEXT step; probs use pre-update mask
    }
  }
  __syncthreads();

  const int sel = sel_s;
  if(tid < TT){
    float p = __expf(sc[tid] - M_s) / S_s;
    out[(size_t)b*TT*TT + (size_t)s*TT + tid] = fmaxf(p, 1e-9f);
  }
  if(tid < DD){
    dec_in[(size_t)b*DD + tid] = targets[((size_t)b*TT + sel)*DD + tid];
  }
}

extern "C" void kernel_launch(void* const* d_in, const int* in_sizes, int n_in,
                              void* d_out, int out_size, void* d_ws, size_t ws_size,
                              hipStream_t stream)
{
  (void)in_sizes; (void)n_in; (void)out_size; (void)ws_size;
  const float* targets  = (const float*)d_in[0];
  const float* h0       = (const float*)d_in[1];
  const float* c0       = (const float*)d_in[2];
  const float* enc_w_ih = (const float*)d_in[3];
  const float* enc_w_hh = (const float*)d_in[4];
  const float* enc_b_ih = (const float*)d_in[5];
  const float* enc_b_hh = (const float*)d_in[6];
  const float* dec_w_ih = (const float*)d_in[7];
  const float* dec_w_hh = (const float*)d_in[8];
  const float* dec_b_ih = (const float*)d_in[9];
  const float* dec_b_hh = (const float*)d_in[10];
  const float* W1       = (const float*)d_in[11];
  const float* W2       = (const float*)d_in[12];
  const float* vt       = (const float*)d_in[13];
  float* out = (float*)d_out;

  // workspace carve-up (~222 MB)
  float* ws      = (float*)d_ws;
  float* blend1  = ws;                               // B*T*256
  float* hA      = blend1 + (size_t)BB*TT*256;       // B*256 each
  float* hB      = hA + (size_t)BB*HH;
  float* cA      = hB + (size_t)BB*HH;
  float* cB      = cA + (size_t)BB*HH;
  float* blend2  = cB + (size_t)BB*HH;               // B*256
  float* dec_in  = blend2 + (size_t)BB*HH;           // B*128
  int*   selected= (int*)(dec_in + (size_t)BB*DD);   // B*T ints

  k_zero_i32<<<(BB*TT + 255)/256, 256, 0, stream>>>(selected, BB*TT);

  // ---- encoder: h written both to h-buffer and into blend1 slot (pre-W1) ----
  // parity: step t WRITES (t even -> hA, t odd -> hB); step t READS what t-1 wrote.
  for(int t=0; t<TT; t++){
    const float* Hp = (t==0) ? nullptr : ((t&1) ? hA : hB);
    const float* Cp = (t==0) ? nullptr : ((t&1) ? cA : cB);
    float* Ho = (t&1) ? hB : hA;
    float* Co = (t&1) ? cB : cA;
    k_gates_cell<<<dim3(16,32), 128, 0, stream>>>(
        targets + (size_t)t*DD, TT*DD,
        Hp, enc_w_ih, enc_w_hh, enc_b_ih, enc_b_hh, Cp,
        Ho, Co, blend1 + (size_t)t*256, TT*256);
  }

  // ---- blend1 = enc_states @ W1^T, in place ----
  k_blend1<<<BB*TT/32, 256, 0, stream>>>(blend1, W1);

  // ---- decoder ----
  for(int s=0; s<TT; s++){
    const float* Hp = (s==0) ? h0 : ((s&1) ? hA : hB);
    const float* Cp = (s==0) ? c0 : ((s&1) ? cA : cB);
    float* Ho = (s&1) ? hB : hA;
    float* Co = (s&1) ? cB : cA;
    const float* Xp = (s==0) ? nullptr : dec_in;   // first input is zeros
    k_gates_cell<<<dim3(16,32), 128, 0, stream>>>(
        Xp, DD, Hp, dec_w_ih, dec_w_hh, dec_b_ih, dec_b_hh, Cp,
        Ho, Co, nullptr, 0);
    k_gemm_nt<<<dim3(4,32), 256, 0, stream>>>(Ho, HH, W2, HH, blend2, HH, HH);
    k_scores<<<BB, 256, 0, stream>>>(blend1, blend2, vt, targets, selected,
                                     dec_in, out, s);
  }
}